// Round 11
// baseline (109.843 us; speedup 1.0000x reference)
//
#include <hip/hip_runtime.h>
#include <hip/hip_bf16.h>

// SparseDynamicConv3d: out[n,o] = sum_k sum_c feat[idx[k,n],c] * W[k,c,o]
// Round 11: r10 with DOUBLED outstanding-gather depth (the diagnosed binder:
// random cross-XCD gathers need ~25KB/CU in flight; r10's ring-2 gave ~12KB).
//   - A-frag ring 2 -> 4 deep, aload issued 4 k-steps ahead
//   - bst ring 4 -> 2 (VGPR budget), rows ring-4 unchanged
// prep/wtb/LDS layouts byte-identical to validated r6/r10.

#define NVOX       100000
#define INC        48
#define INC_MAX    64
#define OUTC       64
#define OUTC_MAX   96
#define KOFF       27
#define FEAT_ROW   64                        // bf16 row padded to 128 B
#define FEATB_ELEMS ((NVOX + 1) * FEAT_ROW)  // +1 zero row for idx<0
#define WTB_K      3072                      // shorts per k: 48x64 frag-packed
#define WTB_ELEMS  (KOFF * WTB_K)            // 82944
#define WS_NEED    ((size_t)(FEATB_ELEMS + WTB_ELEMS) * 2)
#define FEAT_THREADS ((NVOX + 1) * 8)        // 800008
#define FEAT_PREP_BLKS ((FEAT_THREADS + 255) / 256)   // 3126
#define WTB_PREP_BLKS  (WTB_ELEMS / 256)     // 324 exact
#define MAIN_BLOCKS 782                      // 782 x 128 rows >= 100000

typedef __attribute__((ext_vector_type(8)))  short short8;
typedef __attribute__((ext_vector_type(4)))  float floatx4;
typedef __attribute__((ext_vector_type(16))) float floatx16;

__device__ __forceinline__ short f2bf(float f) {
    union { __hip_bfloat16 h; short s; } u;
    u.h = __float2bfloat16(f);
    return u.s;
}

// featb: [n][64] bf16, c in [48,64) zero, row NVOX all-zero (idx<0 target).
// wtb:   per k, 384 16B chunks: chunk=(ks*2+nt)*64+lane, elem j =
//        B[c=ks*16+(lane>>5)*8+j][o=nt*32+(lane&31)]  (32x32x16 B-operand).
__global__ void __launch_bounds__(256)
prep_cvt(const float* __restrict__ feat, const float* __restrict__ wk,
         short* __restrict__ featb, short* __restrict__ wtb)
{
    int b = blockIdx.x;
    if (b < FEAT_PREP_BLKS) {
        int t = b * 256 + threadIdx.x;
        if (t < FEAT_THREADS) {
            int g = t >> 3, c8 = (t & 7) * 8;
            short8 p = (short8){0, 0, 0, 0, 0, 0, 0, 0};
            if (g < NVOX && c8 < INC) {
                const floatx4* src = (const floatx4*)(feat + g * INC + c8);
                floatx4 f0 = src[0], f1 = src[1];
                #pragma unroll
                for (int j = 0; j < 4; ++j) { p[j] = f2bf(f0[j]); p[4 + j] = f2bf(f1[j]); }
            }
            *(short8*)(featb + g * FEAT_ROW + c8) = p;
        }
    } else {
        int t = (b - FEAT_PREP_BLKS) * 256 + threadIdx.x;   // < 82944 exact
        int k = t / WTB_K, r = t % WTB_K;
        int chunk = r >> 3, j = r & 7;
        int f = chunk >> 6, lane = chunk & 63;
        int ks = f >> 1, nt = f & 1;
        int c = ks * 16 + (lane >> 5) * 8 + j;      // 0..47, no pad
        int o = nt * 32 + (lane & 31);
        wtb[t] = f2bf(wk[k * (INC_MAX * OUTC_MAX) + c * OUTC_MAX + o]);
    }
}

__global__ void __launch_bounds__(128, 2)
spconv_main(const short* __restrict__ featb, const short* __restrict__ wtb,
            const int* __restrict__ idx, float* __restrict__ out)
{
    __shared__ short Bs[4][WTB_K];   // 4 x 6KB single-k B buffers

    const int tid  = threadIdx.x;    // 0..127
    const int lane = tid & 63;
    const int wave = tid >> 6;       // 0..1
    const int l32  = lane & 31;
    const int hi   = lane >> 5;      // which 8-channel half of each 16-ch k-step

    // XCD-contiguous swizzle (bijective for bid<776, identity tail)
    int bid = blockIdx.x;
    int sb  = (bid < 776) ? ((bid & 7) * 97 + (bid >> 3)) : bid;

    const int m0 = sb * 128 + wave * 64;       // this wave's 64-row base
    const int ra = m0 + l32;                   // lane row, low half
    const int rb = m0 + 32 + l32;              // lane row, high half
    const int rra = (ra < NVOX) ? ra : 0;      // clamped idx addresses
    const int rrb = (rb < NVOX) ? rb : 0;

    floatx16 acc[2][2];              // [mh][nt]
    #pragma unroll
    for (int i = 0; i < 2; ++i)
        #pragma unroll
        for (int j = 0; j < 2; ++j)
            #pragma unroll
            for (int r = 0; r < 16; ++r) acc[i][j][r] = 0.f;

    short8 A[4][2][3];   // [k&3][mh][ks] A-frag ring, 4 k-steps deep
    short8 bst[2][3];    // [k&1][chunk] B-stage ring (3 b128/thread/k)
    int    row0[4], row1[4];   // [k&3] gathered rows (idx<0 -> NVOX zero row)

    auto ldrow = [&](int k) {
        int t0 = idx[k * NVOX + rra];
        int t1 = idx[k * NVOX + rrb];
        row0[k & 3] = (t0 < 0) ? NVOX : t0;
        row1[k & 3] = (t1 < 0) ? NVOX : t1;
    };
    auto aload = [&](int k) {
        const short* p0 = featb + row0[k & 3] * FEAT_ROW + hi * 8;
        const short* p1 = featb + row1[k & 3] * FEAT_ROW + hi * 8;
        #pragma unroll
        for (int ks = 0; ks < 3; ++ks) {
            A[k & 3][0][ks] = *(const short8*)(p0 + ks * 16);
            A[k & 3][1][ks] = *(const short8*)(p1 + ks * 16);
        }
    };
    auto bload = [&](int k) {
        #pragma unroll
        for (int c = 0; c < 3; ++c)
            bst[k & 1][c] = *(const short8*)(wtb + k * WTB_K + (c * 128 + tid) * 8);
    };
    auto commit = [&](int k) {
        #pragma unroll
        for (int c = 0; c < 3; ++c)
            *(short8*)&Bs[k & 3][(c * 128 + tid) * 8] = bst[k & 1][c];
    };
    auto compute = [&](int k) {
        #pragma unroll
        for (int ks = 0; ks < 3; ++ks) {
            short8 b0 = *(const short8*)&Bs[k & 3][((ks * 2 + 0) * 64 + lane) * 8];
            short8 b1 = *(const short8*)&Bs[k & 3][((ks * 2 + 1) * 64 + lane) * 8];
            acc[0][0] = __builtin_amdgcn_mfma_f32_32x32x16_bf16(A[k & 3][0][ks], b0, acc[0][0], 0, 0, 0);
            acc[0][1] = __builtin_amdgcn_mfma_f32_32x32x16_bf16(A[k & 3][0][ks], b1, acc[0][1], 0, 0, 0);
            acc[1][0] = __builtin_amdgcn_mfma_f32_32x32x16_bf16(A[k & 3][1][ks], b0, acc[1][0], 0, 0, 0);
            acc[1][1] = __builtin_amdgcn_mfma_f32_32x32x16_bf16(A[k & 3][1][ks], b1, acc[1][1], 0, 0, 0);
        }
    };

    // ---- prologue: rows 0..5, A 0..3 in flight, B 0..1 staged ----
    ldrow(0); ldrow(1); ldrow(2); ldrow(3);
    aload(0); aload(1); aload(2); aload(3);
    ldrow(4); ldrow(5);          // slots 0,1 of rows ring (k&3), past aload(0/1) use
    bload(0); bload(1);

    #pragma unroll
    for (int j = 0; j < 14; ++j) {
        const int kk = 2 * j;

        commit(kk);
        if (kk + 1 < KOFF) commit(kk + 1);
        __syncthreads();

        // next pair's B regs; rows two pairs ahead (consumed by aload at j+1)
        if (kk + 2 < KOFF) bload(kk + 2);
        if (kk + 3 < KOFF) bload(kk + 3);
        if (kk + 6 < KOFF) ldrow(kk + 6);
        if (kk + 7 < KOFF) ldrow(kk + 7);

        // compute(k) consumes A[k&3] before aload(k+4) overwrites it (in-order issue)
        compute(kk);
        if (kk + 4 < KOFF) aload(kk + 4);
        if (kk + 1 < KOFF) {
            compute(kk + 1);
            if (kk + 5 < KOFF) aload(kk + 5);
        }
    }

    // ---- epilogue: D col = nt*32+l32, row = (r&3) + 8*(r>>2) + 4*hi ----
    #pragma unroll
    for (int mh = 0; mh < 2; ++mh) {
        #pragma unroll
        for (int r = 0; r < 16; ++r) {
            int g = m0 + mh * 32 + (r & 3) + 8 * (r >> 2) + 4 * hi;
            if (g < NVOX) {
                out[g * OUTC + l32]      = acc[mh][0][r];
                out[g * OUTC + 32 + l32] = acc[mh][1][r];
            }
        }
    }
}

// Safety fallback (only if workspace too small): plain fp32.
__global__ void __launch_bounds__(256)
spconv_fallback(const float* __restrict__ feat, const float* __restrict__ wk,
                const int* __restrict__ idx, float* __restrict__ out)
{
    int t = blockIdx.x * 256 + threadIdx.x;
    if (t >= NVOX * OUTC) return;
    int n = t >> 6, o = t & 63;
    float s = 0.f;
    for (int k = 0; k < KOFF; ++k) {
        int g = idx[k * NVOX + n];
        if (g >= 0) {
            const float* fr = feat + g * INC;
            const float* wr = wk + k * (INC_MAX * OUTC_MAX) + o;
            #pragma unroll 8
            for (int c = 0; c < INC; ++c) s += fr[c] * wr[c * OUTC_MAX];
        }
    }
    out[t] = s;
}

extern "C" void kernel_launch(void* const* d_in, const int* in_sizes, int n_in,
                              void* d_out, int out_size, void* d_ws, size_t ws_size,
                              hipStream_t stream) {
    const float* feat = (const float*)d_in[0];
    const float* wk   = (const float*)d_in[1];
    const int*   idx  = (const int*)d_in[2];
    float* out = (float*)d_out;

    if (ws_size >= WS_NEED) {
        short* featb = (short*)d_ws;
        short* wtb   = featb + FEATB_ELEMS;
        prep_cvt<<<FEAT_PREP_BLKS + WTB_PREP_BLKS, 256, 0, stream>>>(feat, wk, featb, wtb);
        spconv_main<<<MAIN_BLOCKS, 128, 0, stream>>>(featb, wtb, idx, out);
    } else {
        spconv_fallback<<<(NVOX * OUTC + 255) / 256, 256, 0, stream>>>(feat, wk, idx, out);
    }
}